// Round 9
// baseline (260.642 us; speedup 1.0000x reference)
//
#include <hip/hip_runtime.h>
#include <stdint.h>

// B=4096, IN=1024, L0=2048, L1=1024, H=128, NT=512, T=0.1, EPS=1e-5
// Round 9: round-8 base (240 us) + ONE lever: GEMM2 gets a dedicated 128x64-tile
// kernel (128 threads, 2 waves, grid 16x32 = 512 blocks -> 2 blocks/CU) so a
// co-resident block covers the other's staging stalls. Per-wave MFMA/ds_read
// profile identical to the 128x128 kernel; y2 bit-identical. All else unchanged.

typedef __attribute__((ext_vector_type(8))) __bf16 bf16x8;
typedef __attribute__((ext_vector_type(4))) float f32x4;

__device__ __forceinline__ unsigned short f2bf(float f) {
  unsigned int u = __float_as_uint(f);
  unsigned int r = (u + 0x7fffu + ((u >> 16) & 1u)) >> 16;  // RNE
  return (unsigned short)r;
}
__device__ __forceinline__ float bf2f(unsigned short h) {
  return __uint_as_float(((unsigned int)h) << 16);
}

__device__ __forceinline__ void gll16(const void* g, void* l) {
  __builtin_amdgcn_global_load_lds(
      (const __attribute__((address_space(1))) unsigned int*)g,
      (__attribute__((address_space(3))) unsigned int*)l, 16, 0, 0);
}

// ---------------- transpose + split convert tile (device body) ----------------
__device__ __forceinline__ void tsplit_tile(const float* __restrict__ in,
                                            unsigned short* __restrict__ ohi,
                                            unsigned short* __restrict__ olo,
                                            int R, int C, int bx, int by, int tid) {
  __shared__ unsigned short th[32][33];
  __shared__ unsigned short tl[32][33];
  int c0 = bx * 32, r0 = by * 32;
  int tx = tid & 31, ty = tid >> 5;  // 32 x 8
#pragma unroll
  for (int i = 0; i < 32; i += 8) {
    float v = in[(size_t)(r0 + ty + i) * C + c0 + tx];
    unsigned short h = f2bf(v);
    th[ty + i][tx] = h;
    tl[ty + i][tx] = f2bf(v - bf2f(h));
  }
  __syncthreads();
#pragma unroll
  for (int i = 0; i < 32; i += 8) {
    ohi[(size_t)(c0 + ty + i) * R + r0 + tx] = th[tx][ty + i];
    olo[(size_t)(c0 + ty + i) * R + r0 + tx] = tl[tx][ty + i];
  }
}

// ---------------- fused prep: convert x, transpose w1..w4, decoder norm ----------------
__global__ void kprep(const float4* __restrict__ x4, ushort4* __restrict__ xhi4,
                      ushort4* __restrict__ xlo4,
                      const float* __restrict__ w1, unsigned short* __restrict__ w1th,
                      unsigned short* __restrict__ w1tl,
                      const float* __restrict__ w2, unsigned short* __restrict__ w2th,
                      unsigned short* __restrict__ w2tl,
                      const float* __restrict__ w3, unsigned short* __restrict__ w3th,
                      unsigned short* __restrict__ w3tl,
                      const float* __restrict__ w4, unsigned short* __restrict__ w4th,
                      unsigned short* __restrict__ w4tl,
                      const float* __restrict__ dw, float* __restrict__ decode,
                      unsigned short* __restrict__ decT, float* __restrict__ diag) {
  int z = blockIdx.x;
  int tid = threadIdx.x;
  if (z < 4096) {
    int i = z * 256 + tid;
    float4 v = x4[i];
    ushort4 h, l;
    h.x = f2bf(v.x); l.x = f2bf(v.x - bf2f(h.x));
    h.y = f2bf(v.y); l.y = f2bf(v.y - bf2f(h.y));
    h.z = f2bf(v.z); l.z = f2bf(v.z - bf2f(h.z));
    h.w = f2bf(v.w); l.w = f2bf(v.w - bf2f(h.w));
    xhi4[i] = h; xlo4[i] = l;
  } else if (z < 6144) {
    int zz = z - 4096;
    tsplit_tile(w1, w1th, w1tl, 1024, 2048, zz & 63, zz >> 6, tid);
  } else if (z < 8192) {
    int zz = z - 6144;
    tsplit_tile(w2, w2th, w2tl, 2048, 1024, zz & 31, zz >> 5, tid);
  } else if (z < 8320) {
    int zz = z - 8192;
    tsplit_tile(w3, w3th, w3tl, 1024, 128, zz & 3, zz >> 2, tid);
  } else if (z < 8336) {
    int zz = z - 8320;
    tsplit_tile(w4, w4th, w4tl, 128, 128, zz & 3, zz >> 2, tid);
  } else {
    int h = z - 8336;
    __shared__ float red[256];
    float s = 0.f;
    for (int i = tid; i < 1024; i += 256) s += dw[h * 1024 + i];
    red[tid] = s;
    __syncthreads();
    for (int k = 128; k > 0; k >>= 1) {
      if (tid < k) red[tid] += red[tid + k];
      __syncthreads();
    }
    float d = fabsf(red[0]);
    if (tid == 0) diag[h] = d;
    float inv = 1.0f / d;
    for (int i = tid; i < 1024; i += 256) {
      float v = fabsf(dw[h * 1024 + i]) * inv;
      decode[h * 1024 + i] = v;
      decT[i * 128 + h] = f2bf(v);
    }
  }
}

// ---------------- split-bf16 3-pass MFMA GEMM, LDS double-buffered, 128x128 ----------------
__global__ __launch_bounds__(256) void kgemm3p(
    const unsigned short* __restrict__ Ah, const unsigned short* __restrict__ Al,
    const unsigned short* __restrict__ Bh, const unsigned short* __restrict__ Bl,
    const float* __restrict__ bias, float* __restrict__ C, int N, int K, int kLen,
    float* __restrict__ bnps, float* __restrict__ bnpq, const float* __restrict__ diag) {
  __shared__ unsigned short AsB[2][2][4096];  // [buf][hi|lo][128 rows x 32 k] 32KB
  __shared__ unsigned short BsB[2][2][4096];  // 32KB
  float (*sred)[2][128] = (float(*)[2][128])AsB;  // alias; used only after final barrier
  int tid = threadIdx.x;
  int lane = tid & 63;
  int wave = tid >> 6;
  int wm = wave >> 1, wn = wave & 1;
  int rowBase = blockIdx.x * 128;
  int colBase = blockIdx.y * 128;
  int kOff = blockIdx.z * kLen;
  C += (size_t)blockIdx.z * gridDim.x * 128 * N;  // split-K partial stripe

  f32x4 acc[4][4];
#pragma unroll
  for (int i = 0; i < 4; i++)
#pragma unroll
    for (int j = 0; j < 4; j++) acc[i][j] = (f32x4){0.f, 0.f, 0.f, 0.f};

  int r4 = tid >> 2;       // 0..63
  int kc = (tid & 3) * 8;  // 0,8,16,24
  int lr = lane & 15;
  int lk = (lane >> 4) * 8;

  const unsigned short* Ah0 = Ah + (size_t)(rowBase + r4) * K + kOff + kc;
  const unsigned short* Al0 = Al + (size_t)(rowBase + r4) * K + kOff + kc;
  const unsigned short* Bh0 = Bh + (size_t)(colBase + r4) * K + kOff + kc;
  const unsigned short* Bl0 = Bl + (size_t)(colBase + r4) * K + kOff + kc;
  size_t rstep = (size_t)64 * K;

  auto STAGE = [&](int k0, int buf) {
    char* aD = (char*)AsB + buf * 16384 + tid * 16;
    char* bD = (char*)BsB + buf * 16384 + tid * 16;
    gll16(Ah0 + k0, aD);        gll16(Ah0 + k0 + rstep, aD + 4096);
    gll16(Al0 + k0, aD + 8192); gll16(Al0 + k0 + rstep, aD + 12288);
    gll16(Bh0 + k0, bD);        gll16(Bh0 + k0 + rstep, bD + 4096);
    gll16(Bl0 + k0, bD + 8192); gll16(Bl0 + k0 + rstep, bD + 12288);
  };

  STAGE(0, 0);
  __syncthreads();  // compiler drains vmcnt before barrier

  int nk = kLen >> 5;
  for (int kt = 0; kt < nk; ++kt) {
    int cur = kt & 1;
    if (kt + 1 < nk) STAGE((kt + 1) << 5, cur ^ 1);

    bf16x8 ah[4], al[4], bh[4], bl[4];
    const unsigned short* Ac = &AsB[cur][0][0];
    const unsigned short* Bc = &BsB[cur][0][0];
#pragma unroll
    for (int mi = 0; mi < 4; mi++) {
      int ro = (wm * 64 + mi * 16 + lr) * 32 + lk;
      int co = (wn * 64 + mi * 16 + lr) * 32 + lk;
      ah[mi] = *(const bf16x8*)&Ac[ro];
      al[mi] = *(const bf16x8*)&Ac[4096 + ro];
      bh[mi] = *(const bf16x8*)&Bc[co];
      bl[mi] = *(const bf16x8*)&Bc[4096 + co];
    }

#pragma unroll
    for (int mi = 0; mi < 4; mi++)
#pragma unroll
      for (int ni = 0; ni < 4; ni++) {
        acc[mi][ni] = __builtin_amdgcn_mfma_f32_16x16x32_bf16(ah[mi], bh[ni], acc[mi][ni], 0, 0, 0);
        acc[mi][ni] = __builtin_amdgcn_mfma_f32_16x16x32_bf16(ah[mi], bl[ni], acc[mi][ni], 0, 0, 0);
        acc[mi][ni] = __builtin_amdgcn_mfma_f32_16x16x32_bf16(al[mi], bh[ni], acc[mi][ni], 0, 0, 0);
      }
    __syncthreads();
  }

  int lg = lane >> 4;
  if (diag) {
#pragma unroll
    for (int mi = 0; mi < 4; mi++)
#pragma unroll
      for (int ni = 0; ni < 4; ni++) {
        int col = colBase + wn * 64 + ni * 16 + lr;
        float bv = bias ? bias[col] : 0.0f;
        float dg = diag[col];
#pragma unroll
        for (int j = 0; j < 4; j++) {
          int row = rowBase + wm * 64 + mi * 16 + lg * 4 + j;
          float r = fabsf(acc[mi][ni][j] + bv) * dg;
          C[(size_t)row * N + col] = fminf(fmaxf(r, 1e-10f), 1e7f);
        }
      }
  } else {
    float s[4] = {0.f, 0.f, 0.f, 0.f}, q[4] = {0.f, 0.f, 0.f, 0.f};
#pragma unroll
    for (int mi = 0; mi < 4; mi++)
#pragma unroll
      for (int ni = 0; ni < 4; ni++) {
        int col = colBase + wn * 64 + ni * 16 + lr;
        float bv = bias ? bias[col] : 0.0f;
#pragma unroll
        for (int j = 0; j < 4; j++) {
          int row = rowBase + wm * 64 + mi * 16 + lg * 4 + j;
          float v = acc[mi][ni][j] + bv;
          C[(size_t)row * N + col] = v;
          s[ni] += v;
          q[ni] += v * v;
        }
      }
    if (bnps) {
#pragma unroll
      for (int ni = 0; ni < 4; ni++) {
        s[ni] += __shfl_xor(s[ni], 16); s[ni] += __shfl_xor(s[ni], 32);
        q[ni] += __shfl_xor(q[ni], 16); q[ni] += __shfl_xor(q[ni], 32);
      }
      if (lg == 0) {
#pragma unroll
        for (int ni = 0; ni < 4; ni++) {
          sred[wm][0][wn * 64 + ni * 16 + lr] = s[ni];
          sred[wm][1][wn * 64 + ni * 16 + lr] = q[ni];
        }
      }
      __syncthreads();
      if (tid < 128) {
        bnps[(size_t)blockIdx.x * N + colBase + tid] = sred[0][0][tid] + sred[1][0][tid];
        bnpq[(size_t)blockIdx.x * N + colBase + tid] = sred[0][1][tid] + sred[1][1][tid];
      }
    }
  }
}

// ---------------- split-bf16 3-pass GEMM, 128x64 tile, 128 threads (2 waves) ----------------
// grid (N/64, M/128); col-block fastest so blocks sharing an A row-panel run adjacently.
// 2 blocks/CU -> cross-block stall cover. Per-wave profile identical to kgemm3p.
// Always: C = A@B^T + bias, plus BN column partials (stripe = blockIdx.y).
__global__ __launch_bounds__(128) void kgemm3p_n64(
    const unsigned short* __restrict__ Ah, const unsigned short* __restrict__ Al,
    const unsigned short* __restrict__ Bh, const unsigned short* __restrict__ Bl,
    const float* __restrict__ bias, float* __restrict__ C, int N, int K,
    float* __restrict__ bnps, float* __restrict__ bnpq) {
  __shared__ unsigned short AsB[2][2][4096];  // [buf][hi|lo][128 x 32] 32KB
  __shared__ unsigned short BsB[2][2][2048];  // [buf][hi|lo][64 x 32]  16KB
  float (*sred)[2][64] = (float(*)[2][64])AsB;  // alias; used after final barrier
  int tid = threadIdx.x;
  int lane = tid & 63;
  int wm = tid >> 6;  // wave 0/1 = row half
  int rowBase = blockIdx.y * 128;
  int colBase = blockIdx.x * 64;

  f32x4 acc[4][4];
#pragma unroll
  for (int i = 0; i < 4; i++)
#pragma unroll
    for (int j = 0; j < 4; j++) acc[i][j] = (f32x4){0.f, 0.f, 0.f, 0.f};

  int r4 = tid >> 2;       // 0..31
  int kc = (tid & 3) * 8;  // 0,8,16,24
  int lr = lane & 15;
  int lk = (lane >> 4) * 8;

  const unsigned short* Ah0 = Ah + (size_t)(rowBase + r4) * K + kc;
  const unsigned short* Al0 = Al + (size_t)(rowBase + r4) * K + kc;
  const unsigned short* Bh0 = Bh + (size_t)(colBase + r4) * K + kc;
  const unsigned short* Bl0 = Bl + (size_t)(colBase + r4) * K + kc;
  size_t rstep = (size_t)32 * K;  // 32 rows per staging round

  auto STAGE = [&](int k0, int buf) {
    char* aD = (char*)AsB + buf * 16384 + tid * 16;
    char* bD = (char*)BsB + buf * 8192 + tid * 16;
    gll16(Ah0 + k0, aD);
    gll16(Ah0 + k0 + rstep, aD + 2048);
    gll16(Ah0 + k0 + 2 * rstep, aD + 4096);
    gll16(Ah0 + k0 + 3 * rstep, aD + 6144);
    gll16(Al0 + k0, aD + 8192);
    gll16(Al0 + k0 + rstep, aD + 10240);
    gll16(Al0 + k0 + 2 * rstep, aD + 12288);
    gll16(Al0 + k0 + 3 * rstep, aD + 14336);
    gll16(Bh0 + k0, bD);
    gll16(Bh0 + k0 + rstep, bD + 2048);
    gll16(Bl0 + k0, bD + 4096);
    gll16(Bl0 + k0 + rstep, bD + 6144);
  };

  STAGE(0, 0);
  __syncthreads();

  int nk = K >> 5;
  for (int kt = 0; kt < nk; ++kt) {
    int cur = kt & 1;
    if (kt + 1 < nk) STAGE((kt + 1) << 5, cur ^ 1);

    bf16x8 ah[4], al[4], bh[4], bl[4];
    const unsigned short* Ac = &AsB[cur][0][0];
    const unsigned short* Bc = &BsB[cur][0][0];
#pragma unroll
    for (int mi = 0; mi < 4; mi++) {
      int ro = (wm * 64 + mi * 16 + lr) * 32 + lk;
      int co = (mi * 16 + lr) * 32 + lk;
      ah[mi] = *(const bf16x8*)&Ac[ro];
      al[mi] = *(const bf16x8*)&Ac[4096 + ro];
      bh[mi] = *(const bf16x8*)&Bc[co];
      bl[mi] = *(const bf16x8*)&Bc[2048 + co];
    }

#pragma unroll
    for (int mi = 0; mi < 4; mi++)
#pragma unroll
      for (int ni = 0; ni < 4; ni++) {
        acc[mi][ni] = __builtin_amdgcn_mfma_f32_16x16x32_bf16(ah[mi], bh[ni], acc[mi][ni], 0, 0, 0);
        acc[mi][ni] = __builtin_amdgcn_mfma_f32_16x16x32_bf16(ah[mi], bl[ni], acc[mi][ni], 0, 0, 0);
        acc[mi][ni] = __builtin_amdgcn_mfma_f32_16x16x32_bf16(al[mi], bh[ni], acc[mi][ni], 0, 0, 0);
      }
    __syncthreads();
  }

  int lg = lane >> 4;
  float s[4] = {0.f, 0.f, 0.f, 0.f}, q[4] = {0.f, 0.f, 0.f, 0.f};
#pragma unroll
  for (int mi = 0; mi < 4; mi++)
#pragma unroll
    for (int ni = 0; ni < 4; ni++) {
      int col = colBase + ni * 16 + lr;
      float bv = bias[col];
#pragma unroll
      for (int j = 0; j < 4; j++) {
        int row = rowBase + wm * 64 + mi * 16 + lg * 4 + j;
        float v = acc[mi][ni][j] + bv;
        C[(size_t)row * N + col] = v;
        s[ni] += v;
        q[ni] += v * v;
      }
    }
  // reduce 4 lg-groups within wave, then across the 2 waves via LDS
#pragma unroll
  for (int ni = 0; ni < 4; ni++) {
    s[ni] += __shfl_xor(s[ni], 16); s[ni] += __shfl_xor(s[ni], 32);
    q[ni] += __shfl_xor(q[ni], 16); q[ni] += __shfl_xor(q[ni], 32);
  }
  if (lg == 0) {
#pragma unroll
    for (int ni = 0; ni < 4; ni++) {
      sred[wm][0][ni * 16 + lr] = s[ni];
      sred[wm][1][ni * 16 + lr] = q[ni];
    }
  }
  __syncthreads();
  if (tid < 64) {
    bnps[(size_t)blockIdx.y * N + colBase + tid] = sred[0][0][tid] + sred[1][0][tid];
    bnpq[(size_t)blockIdx.y * N + colBase + tid] = sred[0][1][tid] + sred[1][1][tid];
  }
}

// ---------------- single-pass bf16 GEMM (reconstruction), LDS double-buffered ----------------
__global__ __launch_bounds__(256) void kgemm(
    const unsigned short* __restrict__ A, const unsigned short* __restrict__ BT,
    float* __restrict__ C, int N, int K) {
  __shared__ unsigned short As2[2][4096];
  __shared__ unsigned short Bs2[2][4096];
  int tid = threadIdx.x;
  int lane = tid & 63;
  int wave = tid >> 6;
  int wm = wave >> 1, wn = wave & 1;
  int rowBase = blockIdx.x * 128;
  int colBase = blockIdx.y * 128;

  f32x4 acc[4][4];
#pragma unroll
  for (int i = 0; i < 4; i++)
#pragma unroll
    for (int j = 0; j < 4; j++) acc[i][j] = (f32x4){0.f, 0.f, 0.f, 0.f};

  int r4 = tid >> 2;
  int kc = (tid & 3) * 8;
  int lr = lane & 15;
  int lk = (lane >> 4) * 8;

  const unsigned short* A0 = A + (size_t)(rowBase + r4) * K + kc;
  const unsigned short* B0 = BT + (size_t)(colBase + r4) * K + kc;
  size_t rstep = (size_t)64 * K;

  auto STAGE = [&](int k0, int buf) {
    char* aD = (char*)As2 + buf * 8192 + tid * 16;
    char* bD = (char*)Bs2 + buf * 8192 + tid * 16;
    gll16(A0 + k0, aD); gll16(A0 + k0 + rstep, aD + 4096);
    gll16(B0 + k0, bD); gll16(B0 + k0 + rstep, bD + 4096);
  };

  STAGE(0, 0);
  __syncthreads();

  int nk = K >> 5;
  for (int kt = 0; kt < nk; ++kt) {
    int cur = kt & 1;
    if (kt + 1 < nk) STAGE((kt + 1) << 5, cur ^ 1);
    bf16x8 af[4], bfr[4];
#pragma unroll
    for (int mi = 0; mi < 4; mi++) {
      af[mi] = *(const bf16x8*)&As2[cur][(wm * 64 + mi * 16 + lr) * 32 + lk];
      bfr[mi] = *(const bf16x8*)&Bs2[cur][(wn * 64 + mi * 16 + lr) * 32 + lk];
    }
#pragma unroll
    for (int mi = 0; mi < 4; mi++)
#pragma unroll
      for (int ni = 0; ni < 4; ni++)
        acc[mi][ni] = __builtin_amdgcn_mfma_f32_16x16x32_bf16(af[mi], bfr[ni], acc[mi][ni], 0, 0, 0);
    __syncthreads();
  }

  int lg = lane >> 4;
#pragma unroll
  for (int mi = 0; mi < 4; mi++)
#pragma unroll
    for (int ni = 0; ni < 4; ni++) {
      int col = colBase + wn * 64 + ni * 16 + lr;
#pragma unroll
      for (int j = 0; j < 4; j++) {
        int row = rowBase + wm * 64 + mi * 16 + lg * 4 + j;
        C[(size_t)row * N + col] = acc[mi][ni][j];
      }
    }
}

// ---- fused L3 split-K combine + bias + BN column partials ----
__global__ void kcombine_partial(const float* __restrict__ Cp, const float* __restrict__ bias,
                                 float* __restrict__ y, float* __restrict__ ps,
                                 float* __restrict__ pq) {
  int c = threadIdx.x;
  int r0 = blockIdx.x * 128;
  float bv = bias[c];
  float s = 0.f, q = 0.f;
  for (int r = r0; r < r0 + 128; ++r) {
    float a = Cp[(size_t)r * 128 + c];
    a += Cp[524288 + (size_t)r * 128 + c];
    a += Cp[1048576 + (size_t)r * 128 + c];
    a += Cp[1572864 + (size_t)r * 128 + c];
    a += bv;
    y[(size_t)r * 128 + c] = a;
    s += a;
    q += a * a;
  }
  ps[blockIdx.x * 128 + c] = s;
  pq[blockIdx.x * 128 + c] = q;
}

__global__ void kbn_final(const float* __restrict__ ps, const float* __restrict__ pq,
                          const float* __restrict__ g, const float* __restrict__ b,
                          float* __restrict__ scale, float* __restrict__ shift, int N,
                          int stripes) {
  int c = blockIdx.x * blockDim.x + threadIdx.x;
  if (c >= N) return;
  float s = 0.f, q = 0.f;
  for (int i = 0; i < stripes; ++i) {
    s += ps[i * N + c];
    q += pq[i * N + c];
  }
  float m = s * (1.0f / 4096.0f);
  float var = q * (1.0f / 4096.0f) - m * m;
  float sc = g[c] * rsqrtf(var + 1e-5f);
  scale[c] = sc;
  shift[c] = b[c] - m * sc;
}

// BN apply + ReLU + split-bf16 output, 4 elems/thread
__global__ void kbn_apply_split4(const float4* __restrict__ y, const float* __restrict__ scale,
                                 const float* __restrict__ shift, ushort4* __restrict__ hhi,
                                 ushort4* __restrict__ hlo, int mask) {
  int i = blockIdx.x * blockDim.x + threadIdx.x;
  int c0 = (i << 2) & mask;
  float4 v = y[i];
  ushort4 h, l;
  float t;
  t = v.x * scale[c0] + shift[c0];         t = t > 0.f ? t : 0.f; h.x = f2bf(t); l.x = f2bf(t - bf2f(h.x));
  t = v.y * scale[c0 + 1] + shift[c0 + 1]; t = t > 0.f ? t : 0.f; h.y = f2bf(t); l.y = f2bf(t - bf2f(h.y));
  t = v.z * scale[c0 + 2] + shift[c0 + 2]; t = t > 0.f ? t : 0.f; h.z = f2bf(t); l.z = f2bf(t - bf2f(h.z));
  t = v.w * scale[c0 + 3] + shift[c0 + 3]; t = t > 0.f ? t : 0.f; h.w = f2bf(t); l.w = f2bf(t - bf2f(h.w));
  hhi[i] = h;
  hlo[i] = l;
}

// ---------------- Poisson rsample with early exit ----------------
__global__ __launch_bounds__(256) void kpoisson(const float* __restrict__ u,
                                                const float* __restrict__ rate,
                                                float* __restrict__ samples,
                                                unsigned short* __restrict__ sb) {
  int tid = blockIdx.x * 256 + threadIdx.x;
  int h = tid & 127;
  int b = tid >> 7;
  float r = rate[tid];
  float inv = 1.0f / r;
  const float* up = u + (size_t)b * (512 * 128) + h;
  float t = 0.f, s = 0.f;
  for (int nt = 0; nt < 512; ++nt) {
    float uv = up[(size_t)nt * 128];
    t += (-__logf(uv)) * inv;
    float z = (t - 1.0f) * 10.0f;
    s += __frcp_rn(1.0f + __expf(z));
    if (t > 4.0f) break;
  }
  samples[tid] = s;
  sb[tid] = f2bf(s);
}

extern "C" void kernel_launch(void* const* d_in, const int* in_sizes, int n_in,
                              void* d_out, int out_size, void* d_ws, size_t ws_size,
                              hipStream_t stream) {
  const float* x = (const float*)d_in[0];
  const float* u = (const float*)d_in[1];
  const float* w1 = (const float*)d_in[2];
  const float* b1 = (const float*)d_in[3];
  const float* g1 = (const float*)d_in[4];
  const float* bb1 = (const float*)d_in[5];
  const float* w2 = (const float*)d_in[6];
  const float* b2 = (const float*)d_in[7];
  const float* g2 = (const float*)d_in[8];
  const float* bb2 = (const float*)d_in[9];
  const float* w3 = (const float*)d_in[10];
  const float* b3 = (const float*)d_in[11];
  const float* g3 = (const float*)d_in[12];
  const float* bb3 = (const float*)d_in[13];
  const float* w4 = (const float*)d_in[14];
  const float* b4 = (const float*)d_in[15];
  const float* dw = (const float*)d_in[16];

  float* out = (float*)d_out;
  float* out_xrec = out;            // [4096][1024]
  float* out_samp = out + 4194304;  // [4096][128]
  float* out_rate = out + 4718592;  // [4096][128]
  float* out_dec = out + 5242880;   // [128][1024]

  char* w = (char*)d_ws;
  unsigned short* xhi = (unsigned short*)w;  w += 8388608;   // [4096][1024]
  unsigned short* xlo = (unsigned short*)w;  w += 8388608;
  unsigned short* w1th = (unsigned short*)w; w += 4194304;   // [2048][1024]
  unsigned short* w1tl = (unsigned short*)w; w += 4194304;
  unsigned short* w2th = (unsigned short*)w; w += 4194304;   // [1024][2048]
  unsigned short* w2tl = (unsigned short*)w; w += 4194304;
  unsigned short* w3th = (unsigned short*)w; w += 262144;    // [128][1024]
  unsigned short* w3tl = (unsigned short*)w; w += 262144;
  unsigned short* w4th = (unsigned short*)w; w += 32768;     // [128][128]
  unsigned short* w4tl = (unsigned short*)w; w += 32768;
  float* y = (float*)w;             w += 33554432;           // y1 [4096][2048], reused as y2
  unsigned short* h1h = (unsigned short*)w; w += 16777216;   // [4096][2048]
  unsigned short* h1l = (unsigned short*)w; w += 16777216;
  unsigned short* h2h = (unsigned short*)w; w += 8388608;    // [4096][1024]
  unsigned short* h2l = (unsigned short*)w; w += 8388608;
  unsigned short* h3h = (unsigned short*)w; w += 1048576;    // [4096][128]
  unsigned short* h3l = (unsigned short*)w; w += 1048576;
  float* y3 = (float*)w;            w += 2097152;            // [4096][128]
  float* Cp = (float*)w;            w += 8388608;            // split-K partials [4][4096][128]
  unsigned short* sb = (unsigned short*)w; w += 1048576;     // samples bf16
  unsigned short* dct = (unsigned short*)w; w += 262144;     // decode^T bf16 [1024][128]
  float* diag = (float*)w;          w += 1024;
  float* ps = (float*)w;            w += 262144;             // [<=32][N<=2048]
  float* pq = (float*)w;            w += 262144;
  float* scale = (float*)w;         w += 8192;
  float* shift = (float*)w;         w += 8192;

  // --- fused prep ---
  kprep<<<8464, 256, 0, stream>>>((const float4*)x, (ushort4*)xhi, (ushort4*)xlo,
                                  w1, w1th, w1tl, w2, w2th, w2tl, w3, w3th, w3tl,
                                  w4, w4th, w4tl, dw, out_dec, dct, diag);

  // --- encoder layer 1 (BN partials fused into GEMM epilogue) ---
  kgemm3p<<<dim3(32, 16), 256, 0, stream>>>(xhi, xlo, w1th, w1tl, b1, y, 2048, 1024, 1024,
                                            ps, pq, nullptr);
  kbn_final<<<8, 256, 0, stream>>>(ps, pq, g1, bb1, scale, shift, 2048, 32);
  kbn_apply_split4<<<8192, 256, 0, stream>>>((const float4*)y, scale, shift, (ushort4*)h1h,
                                             (ushort4*)h1l, 2047);

  // --- encoder layer 2: 128x64 tiles, 512 blocks -> 2 blocks/CU ---
  kgemm3p_n64<<<dim3(16, 32), 128, 0, stream>>>(h1h, h1l, w2th, w2tl, b2, y, 1024, 2048,
                                                ps, pq);
  kbn_final<<<4, 256, 0, stream>>>(ps, pq, g2, bb2, scale, shift, 1024, 32);
  kbn_apply_split4<<<4096, 256, 0, stream>>>((const float4*)y, scale, shift, (ushort4*)h2h,
                                             (ushort4*)h2l, 1023);

  // --- encoder layer 3 (split-K=4) ---
  kgemm3p<<<dim3(32, 1, 4), 256, 0, stream>>>(h2h, h2l, w3th, w3tl, nullptr, Cp, 128, 1024, 256,
                                              nullptr, nullptr, nullptr);
  kcombine_partial<<<32, 128, 0, stream>>>(Cp, b3, y3, ps, pq);
  kbn_final<<<1, 128, 0, stream>>>(ps, pq, g3, bb3, scale, shift, 128, 32);
  kbn_apply_split4<<<512, 256, 0, stream>>>((const float4*)y3, scale, shift, (ushort4*)h3h,
                                            (ushort4*)h3l, 127);

  // --- lambda head + rate (fused epilogue) ---
  kgemm3p<<<dim3(32, 1), 256, 0, stream>>>(h3h, h3l, w4th, w4tl, b4, out_rate, 128, 128, 128,
                                           nullptr, nullptr, diag);

  // --- Poisson rsample ---
  kpoisson<<<2048, 256, 0, stream>>>(u, out_rate, out_samp, sb);

  // --- reconstruction ---
  kgemm<<<dim3(32, 8), 256, 0, stream>>>(sb, dct, out_xrec, 1024, 128);
}

// Round 10
// 239.293 us; speedup vs baseline: 1.0892x; 1.0892x over previous
//
#include <hip/hip_runtime.h>
#include <stdint.h>

// B=4096, IN=1024, L0=2048, L1=1024, H=128, NT=512, T=0.1, EPS=1e-5
// Round 10: exact round-8 structure (240 us, proven) with ONE tweak:
// kpoisson early-exit threshold 4.0 -> 2.5 (truncation bound 1.6e-4 << 0.18).
// Round-9's 128x64 GEMM2 reverted: +50% staged bytes cost ~+20 us (3rd failed
// GEMM restructure; 2-barrier dbuf 128^2 at min block count is the optimum here).

typedef __attribute__((ext_vector_type(8))) __bf16 bf16x8;
typedef __attribute__((ext_vector_type(4))) float f32x4;

__device__ __forceinline__ unsigned short f2bf(float f) {
  unsigned int u = __float_as_uint(f);
  unsigned int r = (u + 0x7fffu + ((u >> 16) & 1u)) >> 16;  // RNE
  return (unsigned short)r;
}
__device__ __forceinline__ float bf2f(unsigned short h) {
  return __uint_as_float(((unsigned int)h) << 16);
}

__device__ __forceinline__ void gll16(const void* g, void* l) {
  __builtin_amdgcn_global_load_lds(
      (const __attribute__((address_space(1))) unsigned int*)g,
      (__attribute__((address_space(3))) unsigned int*)l, 16, 0, 0);
}

// ---------------- transpose + split convert tile (device body) ----------------
__device__ __forceinline__ void tsplit_tile(const float* __restrict__ in,
                                            unsigned short* __restrict__ ohi,
                                            unsigned short* __restrict__ olo,
                                            int R, int C, int bx, int by, int tid) {
  __shared__ unsigned short th[32][33];
  __shared__ unsigned short tl[32][33];
  int c0 = bx * 32, r0 = by * 32;
  int tx = tid & 31, ty = tid >> 5;  // 32 x 8
#pragma unroll
  for (int i = 0; i < 32; i += 8) {
    float v = in[(size_t)(r0 + ty + i) * C + c0 + tx];
    unsigned short h = f2bf(v);
    th[ty + i][tx] = h;
    tl[ty + i][tx] = f2bf(v - bf2f(h));
  }
  __syncthreads();
#pragma unroll
  for (int i = 0; i < 32; i += 8) {
    ohi[(size_t)(c0 + ty + i) * R + r0 + tx] = th[tx][ty + i];
    olo[(size_t)(c0 + ty + i) * R + r0 + tx] = tl[tx][ty + i];
  }
}

// ---------------- fused prep: convert x, transpose w1..w4, decoder norm ----------------
__global__ void kprep(const float4* __restrict__ x4, ushort4* __restrict__ xhi4,
                      ushort4* __restrict__ xlo4,
                      const float* __restrict__ w1, unsigned short* __restrict__ w1th,
                      unsigned short* __restrict__ w1tl,
                      const float* __restrict__ w2, unsigned short* __restrict__ w2th,
                      unsigned short* __restrict__ w2tl,
                      const float* __restrict__ w3, unsigned short* __restrict__ w3th,
                      unsigned short* __restrict__ w3tl,
                      const float* __restrict__ w4, unsigned short* __restrict__ w4th,
                      unsigned short* __restrict__ w4tl,
                      const float* __restrict__ dw, float* __restrict__ decode,
                      unsigned short* __restrict__ decT, float* __restrict__ diag) {
  int z = blockIdx.x;
  int tid = threadIdx.x;
  if (z < 4096) {
    int i = z * 256 + tid;
    float4 v = x4[i];
    ushort4 h, l;
    h.x = f2bf(v.x); l.x = f2bf(v.x - bf2f(h.x));
    h.y = f2bf(v.y); l.y = f2bf(v.y - bf2f(h.y));
    h.z = f2bf(v.z); l.z = f2bf(v.z - bf2f(h.z));
    h.w = f2bf(v.w); l.w = f2bf(v.w - bf2f(h.w));
    xhi4[i] = h; xlo4[i] = l;
  } else if (z < 6144) {
    int zz = z - 4096;
    tsplit_tile(w1, w1th, w1tl, 1024, 2048, zz & 63, zz >> 6, tid);
  } else if (z < 8192) {
    int zz = z - 6144;
    tsplit_tile(w2, w2th, w2tl, 2048, 1024, zz & 31, zz >> 5, tid);
  } else if (z < 8320) {
    int zz = z - 8192;
    tsplit_tile(w3, w3th, w3tl, 1024, 128, zz & 3, zz >> 2, tid);
  } else if (z < 8336) {
    int zz = z - 8320;
    tsplit_tile(w4, w4th, w4tl, 128, 128, zz & 3, zz >> 2, tid);
  } else {
    int h = z - 8336;
    __shared__ float red[256];
    float s = 0.f;
    for (int i = tid; i < 1024; i += 256) s += dw[h * 1024 + i];
    red[tid] = s;
    __syncthreads();
    for (int k = 128; k > 0; k >>= 1) {
      if (tid < k) red[tid] += red[tid + k];
      __syncthreads();
    }
    float d = fabsf(red[0]);
    if (tid == 0) diag[h] = d;
    float inv = 1.0f / d;
    for (int i = tid; i < 1024; i += 256) {
      float v = fabsf(dw[h * 1024 + i]) * inv;
      decode[h * 1024 + i] = v;
      decT[i * 128 + h] = f2bf(v);
    }
  }
}

// ---------------- split-bf16 3-pass MFMA GEMM, LDS double-buffered, 128x128 ----------------
__global__ __launch_bounds__(256) void kgemm3p(
    const unsigned short* __restrict__ Ah, const unsigned short* __restrict__ Al,
    const unsigned short* __restrict__ Bh, const unsigned short* __restrict__ Bl,
    const float* __restrict__ bias, float* __restrict__ C, int N, int K, int kLen,
    float* __restrict__ bnps, float* __restrict__ bnpq, const float* __restrict__ diag) {
  __shared__ unsigned short AsB[2][2][4096];  // [buf][hi|lo][128 rows x 32 k] 32KB
  __shared__ unsigned short BsB[2][2][4096];  // 32KB
  float (*sred)[2][128] = (float(*)[2][128])AsB;  // alias; used only after final barrier
  int tid = threadIdx.x;
  int lane = tid & 63;
  int wave = tid >> 6;
  int wm = wave >> 1, wn = wave & 1;
  int rowBase = blockIdx.x * 128;
  int colBase = blockIdx.y * 128;
  int kOff = blockIdx.z * kLen;
  C += (size_t)blockIdx.z * gridDim.x * 128 * N;  // split-K partial stripe

  f32x4 acc[4][4];
#pragma unroll
  for (int i = 0; i < 4; i++)
#pragma unroll
    for (int j = 0; j < 4; j++) acc[i][j] = (f32x4){0.f, 0.f, 0.f, 0.f};

  int r4 = tid >> 2;       // 0..63
  int kc = (tid & 3) * 8;  // 0,8,16,24
  int lr = lane & 15;
  int lk = (lane >> 4) * 8;

  const unsigned short* Ah0 = Ah + (size_t)(rowBase + r4) * K + kOff + kc;
  const unsigned short* Al0 = Al + (size_t)(rowBase + r4) * K + kOff + kc;
  const unsigned short* Bh0 = Bh + (size_t)(colBase + r4) * K + kOff + kc;
  const unsigned short* Bl0 = Bl + (size_t)(colBase + r4) * K + kOff + kc;
  size_t rstep = (size_t)64 * K;

  auto STAGE = [&](int k0, int buf) {
    char* aD = (char*)AsB + buf * 16384 + tid * 16;
    char* bD = (char*)BsB + buf * 16384 + tid * 16;
    gll16(Ah0 + k0, aD);        gll16(Ah0 + k0 + rstep, aD + 4096);
    gll16(Al0 + k0, aD + 8192); gll16(Al0 + k0 + rstep, aD + 12288);
    gll16(Bh0 + k0, bD);        gll16(Bh0 + k0 + rstep, bD + 4096);
    gll16(Bl0 + k0, bD + 8192); gll16(Bl0 + k0 + rstep, bD + 12288);
  };

  STAGE(0, 0);
  __syncthreads();  // compiler drains vmcnt before barrier

  int nk = kLen >> 5;
  for (int kt = 0; kt < nk; ++kt) {
    int cur = kt & 1;
    if (kt + 1 < nk) STAGE((kt + 1) << 5, cur ^ 1);

    bf16x8 ah[4], al[4], bh[4], bl[4];
    const unsigned short* Ac = &AsB[cur][0][0];
    const unsigned short* Bc = &BsB[cur][0][0];
#pragma unroll
    for (int mi = 0; mi < 4; mi++) {
      int ro = (wm * 64 + mi * 16 + lr) * 32 + lk;
      int co = (wn * 64 + mi * 16 + lr) * 32 + lk;
      ah[mi] = *(const bf16x8*)&Ac[ro];
      al[mi] = *(const bf16x8*)&Ac[4096 + ro];
      bh[mi] = *(const bf16x8*)&Bc[co];
      bl[mi] = *(const bf16x8*)&Bc[4096 + co];
    }

#pragma unroll
    for (int mi = 0; mi < 4; mi++)
#pragma unroll
      for (int ni = 0; ni < 4; ni++) {
        acc[mi][ni] = __builtin_amdgcn_mfma_f32_16x16x32_bf16(ah[mi], bh[ni], acc[mi][ni], 0, 0, 0);
        acc[mi][ni] = __builtin_amdgcn_mfma_f32_16x16x32_bf16(ah[mi], bl[ni], acc[mi][ni], 0, 0, 0);
        acc[mi][ni] = __builtin_amdgcn_mfma_f32_16x16x32_bf16(al[mi], bh[ni], acc[mi][ni], 0, 0, 0);
      }
    __syncthreads();
  }

  int lg = lane >> 4;
  if (diag) {
#pragma unroll
    for (int mi = 0; mi < 4; mi++)
#pragma unroll
      for (int ni = 0; ni < 4; ni++) {
        int col = colBase + wn * 64 + ni * 16 + lr;
        float bv = bias ? bias[col] : 0.0f;
        float dg = diag[col];
#pragma unroll
        for (int j = 0; j < 4; j++) {
          int row = rowBase + wm * 64 + mi * 16 + lg * 4 + j;
          float r = fabsf(acc[mi][ni][j] + bv) * dg;
          C[(size_t)row * N + col] = fminf(fmaxf(r, 1e-10f), 1e7f);
        }
      }
  } else {
    float s[4] = {0.f, 0.f, 0.f, 0.f}, q[4] = {0.f, 0.f, 0.f, 0.f};
#pragma unroll
    for (int mi = 0; mi < 4; mi++)
#pragma unroll
      for (int ni = 0; ni < 4; ni++) {
        int col = colBase + wn * 64 + ni * 16 + lr;
        float bv = bias ? bias[col] : 0.0f;
#pragma unroll
        for (int j = 0; j < 4; j++) {
          int row = rowBase + wm * 64 + mi * 16 + lg * 4 + j;
          float v = acc[mi][ni][j] + bv;
          C[(size_t)row * N + col] = v;
          s[ni] += v;
          q[ni] += v * v;
        }
      }
    if (bnps) {
#pragma unroll
      for (int ni = 0; ni < 4; ni++) {
        s[ni] += __shfl_xor(s[ni], 16); s[ni] += __shfl_xor(s[ni], 32);
        q[ni] += __shfl_xor(q[ni], 16); q[ni] += __shfl_xor(q[ni], 32);
      }
      if (lg == 0) {
#pragma unroll
        for (int ni = 0; ni < 4; ni++) {
          sred[wm][0][wn * 64 + ni * 16 + lr] = s[ni];
          sred[wm][1][wn * 64 + ni * 16 + lr] = q[ni];
        }
      }
      __syncthreads();
      if (tid < 128) {
        bnps[(size_t)blockIdx.x * N + colBase + tid] = sred[0][0][tid] + sred[1][0][tid];
        bnpq[(size_t)blockIdx.x * N + colBase + tid] = sred[0][1][tid] + sred[1][1][tid];
      }
    }
  }
}

// ---------------- single-pass bf16 GEMM (reconstruction), LDS double-buffered ----------------
__global__ __launch_bounds__(256) void kgemm(
    const unsigned short* __restrict__ A, const unsigned short* __restrict__ BT,
    float* __restrict__ C, int N, int K) {
  __shared__ unsigned short As2[2][4096];
  __shared__ unsigned short Bs2[2][4096];
  int tid = threadIdx.x;
  int lane = tid & 63;
  int wave = tid >> 6;
  int wm = wave >> 1, wn = wave & 1;
  int rowBase = blockIdx.x * 128;
  int colBase = blockIdx.y * 128;

  f32x4 acc[4][4];
#pragma unroll
  for (int i = 0; i < 4; i++)
#pragma unroll
    for (int j = 0; j < 4; j++) acc[i][j] = (f32x4){0.f, 0.f, 0.f, 0.f};

  int r4 = tid >> 2;
  int kc = (tid & 3) * 8;
  int lr = lane & 15;
  int lk = (lane >> 4) * 8;

  const unsigned short* A0 = A + (size_t)(rowBase + r4) * K + kc;
  const unsigned short* B0 = BT + (size_t)(colBase + r4) * K + kc;
  size_t rstep = (size_t)64 * K;

  auto STAGE = [&](int k0, int buf) {
    char* aD = (char*)As2 + buf * 8192 + tid * 16;
    char* bD = (char*)Bs2 + buf * 8192 + tid * 16;
    gll16(A0 + k0, aD); gll16(A0 + k0 + rstep, aD + 4096);
    gll16(B0 + k0, bD); gll16(B0 + k0 + rstep, bD + 4096);
  };

  STAGE(0, 0);
  __syncthreads();

  int nk = K >> 5;
  for (int kt = 0; kt < nk; ++kt) {
    int cur = kt & 1;
    if (kt + 1 < nk) STAGE((kt + 1) << 5, cur ^ 1);
    bf16x8 af[4], bfr[4];
#pragma unroll
    for (int mi = 0; mi < 4; mi++) {
      af[mi] = *(const bf16x8*)&As2[cur][(wm * 64 + mi * 16 + lr) * 32 + lk];
      bfr[mi] = *(const bf16x8*)&Bs2[cur][(wn * 64 + mi * 16 + lr) * 32 + lk];
    }
#pragma unroll
    for (int mi = 0; mi < 4; mi++)
#pragma unroll
      for (int ni = 0; ni < 4; ni++)
        acc[mi][ni] = __builtin_amdgcn_mfma_f32_16x16x32_bf16(af[mi], bfr[ni], acc[mi][ni], 0, 0, 0);
    __syncthreads();
  }

  int lg = lane >> 4;
#pragma unroll
  for (int mi = 0; mi < 4; mi++)
#pragma unroll
    for (int ni = 0; ni < 4; ni++) {
      int col = colBase + wn * 64 + ni * 16 + lr;
#pragma unroll
      for (int j = 0; j < 4; j++) {
        int row = rowBase + wm * 64 + mi * 16 + lg * 4 + j;
        C[(size_t)row * N + col] = acc[mi][ni][j];
      }
    }
}

// ---- fused L3 split-K combine + bias + BN column partials ----
__global__ void kcombine_partial(const float* __restrict__ Cp, const float* __restrict__ bias,
                                 float* __restrict__ y, float* __restrict__ ps,
                                 float* __restrict__ pq) {
  int c = threadIdx.x;
  int r0 = blockIdx.x * 128;
  float bv = bias[c];
  float s = 0.f, q = 0.f;
  for (int r = r0; r < r0 + 128; ++r) {
    float a = Cp[(size_t)r * 128 + c];
    a += Cp[524288 + (size_t)r * 128 + c];
    a += Cp[1048576 + (size_t)r * 128 + c];
    a += Cp[1572864 + (size_t)r * 128 + c];
    a += bv;
    y[(size_t)r * 128 + c] = a;
    s += a;
    q += a * a;
  }
  ps[blockIdx.x * 128 + c] = s;
  pq[blockIdx.x * 128 + c] = q;
}

__global__ void kbn_final(const float* __restrict__ ps, const float* __restrict__ pq,
                          const float* __restrict__ g, const float* __restrict__ b,
                          float* __restrict__ scale, float* __restrict__ shift, int N,
                          int stripes) {
  int c = blockIdx.x * blockDim.x + threadIdx.x;
  if (c >= N) return;
  float s = 0.f, q = 0.f;
  for (int i = 0; i < stripes; ++i) {
    s += ps[i * N + c];
    q += pq[i * N + c];
  }
  float m = s * (1.0f / 4096.0f);
  float var = q * (1.0f / 4096.0f) - m * m;
  float sc = g[c] * rsqrtf(var + 1e-5f);
  scale[c] = sc;
  shift[c] = b[c] - m * sc;
}

// BN apply + ReLU + split-bf16 output, 4 elems/thread
__global__ void kbn_apply_split4(const float4* __restrict__ y, const float* __restrict__ scale,
                                 const float* __restrict__ shift, ushort4* __restrict__ hhi,
                                 ushort4* __restrict__ hlo, int mask) {
  int i = blockIdx.x * blockDim.x + threadIdx.x;
  int c0 = (i << 2) & mask;
  float4 v = y[i];
  ushort4 h, l;
  float t;
  t = v.x * scale[c0] + shift[c0];         t = t > 0.f ? t : 0.f; h.x = f2bf(t); l.x = f2bf(t - bf2f(h.x));
  t = v.y * scale[c0 + 1] + shift[c0 + 1]; t = t > 0.f ? t : 0.f; h.y = f2bf(t); l.y = f2bf(t - bf2f(h.y));
  t = v.z * scale[c0 + 2] + shift[c0 + 2]; t = t > 0.f ? t : 0.f; h.z = f2bf(t); l.z = f2bf(t - bf2f(h.z));
  t = v.w * scale[c0 + 3] + shift[c0 + 3]; t = t > 0.f ? t : 0.f; h.w = f2bf(t); l.w = f2bf(t - bf2f(h.w));
  hhi[i] = h;
  hlo[i] = l;
}

// ---------------- Poisson rsample with early exit ----------------
// After t > 2.5 every remaining term < sigmoid(-15) = 3.1e-7; truncation
// bound 512 * 3.1e-7 = 1.6e-4 absolute (threshold 0.18).
__global__ __launch_bounds__(256) void kpoisson(const float* __restrict__ u,
                                                const float* __restrict__ rate,
                                                float* __restrict__ samples,
                                                unsigned short* __restrict__ sb) {
  int tid = blockIdx.x * 256 + threadIdx.x;
  int h = tid & 127;
  int b = tid >> 7;
  float r = rate[tid];
  float inv = 1.0f / r;
  const float* up = u + (size_t)b * (512 * 128) + h;
  float t = 0.f, s = 0.f;
  for (int nt = 0; nt < 512; ++nt) {
    float uv = up[(size_t)nt * 128];
    t += (-__logf(uv)) * inv;
    float z = (t - 1.0f) * 10.0f;
    s += __frcp_rn(1.0f + __expf(z));
    if (t > 2.5f) break;
  }
  samples[tid] = s;
  sb[tid] = f2bf(s);
}

extern "C" void kernel_launch(void* const* d_in, const int* in_sizes, int n_in,
                              void* d_out, int out_size, void* d_ws, size_t ws_size,
                              hipStream_t stream) {
  const float* x = (const float*)d_in[0];
  const float* u = (const float*)d_in[1];
  const float* w1 = (const float*)d_in[2];
  const float* b1 = (const float*)d_in[3];
  const float* g1 = (const float*)d_in[4];
  const float* bb1 = (const float*)d_in[5];
  const float* w2 = (const float*)d_in[6];
  const float* b2 = (const float*)d_in[7];
  const float* g2 = (const float*)d_in[8];
  const float* bb2 = (const float*)d_in[9];
  const float* w3 = (const float*)d_in[10];
  const float* b3 = (const float*)d_in[11];
  const float* g3 = (const float*)d_in[12];
  const float* bb3 = (const float*)d_in[13];
  const float* w4 = (const float*)d_in[14];
  const float* b4 = (const float*)d_in[15];
  const float* dw = (const float*)d_in[16];

  float* out = (float*)d_out;
  float* out_xrec = out;            // [4096][1024]
  float* out_samp = out + 4194304;  // [4096][128]
  float* out_rate = out + 4718592;  // [4096][128]
  float* out_dec = out + 5242880;   // [128][1024]

  char* w = (char*)d_ws;
  unsigned short* xhi = (unsigned short*)w;  w += 8388608;   // [4096][1024]
  unsigned short* xlo = (unsigned short*)w;  w += 8388608;
  unsigned short* w1th = (unsigned short*)w; w += 4194304;   // [2048][1024]
  unsigned short* w1tl = (unsigned short*)w; w += 4194304;
  unsigned short* w2th = (unsigned short*)w; w += 4194304;   // [1024][2048]
  unsigned short* w2tl = (unsigned short*)w; w += 4194304;
  unsigned short* w3th = (unsigned short*)w; w += 262144;    // [128][1024]
  unsigned short* w3tl = (unsigned short*)w; w += 262144;
  unsigned short* w4th = (unsigned short*)w; w += 32768;     // [128][128]
  unsigned short* w4tl = (unsigned short*)w; w += 32768;
  float* y = (float*)w;             w += 33554432;           // y1 [4096][2048], reused as y2
  unsigned short* h1h = (unsigned short*)w; w += 16777216;   // [4096][2048]
  unsigned short* h1l = (unsigned short*)w; w += 16777216;
  unsigned short* h2h = (unsigned short*)w; w += 8388608;    // [4096][1024]
  unsigned short* h2l = (unsigned short*)w; w += 8388608;
  unsigned short* h3h = (unsigned short*)w; w += 1048576;    // [4096][128]
  unsigned short* h3l = (unsigned short*)w; w += 1048576;
  float* y3 = (float*)w;            w += 2097152;            // [4096][128]
  float* Cp = (float*)w;            w += 8388608;            // split-K partials [4][4096][128]
  unsigned short* sb = (unsigned short*)w; w += 1048576;     // samples bf16
  unsigned short* dct = (unsigned short*)w; w += 262144;     // decode^T bf16 [1024][128]
  float* diag = (float*)w;          w += 1024;
  float* ps = (float*)w;            w += 262144;             // [<=32][N<=2048]
  float* pq = (float*)w;            w += 262144;
  float* scale = (float*)w;         w += 8192;
  float* shift = (float*)w;         w += 8192;

  // --- fused prep ---
  kprep<<<8464, 256, 0, stream>>>((const float4*)x, (ushort4*)xhi, (ushort4*)xlo,
                                  w1, w1th, w1tl, w2, w2th, w2tl, w3, w3th, w3tl,
                                  w4, w4th, w4tl, dw, out_dec, dct, diag);

  // --- encoder layer 1 (BN partials fused into GEMM epilogue) ---
  kgemm3p<<<dim3(32, 16), 256, 0, stream>>>(xhi, xlo, w1th, w1tl, b1, y, 2048, 1024, 1024,
                                            ps, pq, nullptr);
  kbn_final<<<8, 256, 0, stream>>>(ps, pq, g1, bb1, scale, shift, 2048, 32);
  kbn_apply_split4<<<8192, 256, 0, stream>>>((const float4*)y, scale, shift, (ushort4*)h1h,
                                             (ushort4*)h1l, 2047);

  // --- encoder layer 2 ---
  kgemm3p<<<dim3(32, 8), 256, 0, stream>>>(h1h, h1l, w2th, w2tl, b2, y, 1024, 2048, 2048,
                                           ps, pq, nullptr);
  kbn_final<<<4, 256, 0, stream>>>(ps, pq, g2, bb2, scale, shift, 1024, 32);
  kbn_apply_split4<<<4096, 256, 0, stream>>>((const float4*)y, scale, shift, (ushort4*)h2h,
                                             (ushort4*)h2l, 1023);

  // --- encoder layer 3 (split-K=4) ---
  kgemm3p<<<dim3(32, 1, 4), 256, 0, stream>>>(h2h, h2l, w3th, w3tl, nullptr, Cp, 128, 1024, 256,
                                              nullptr, nullptr, nullptr);
  kcombine_partial<<<32, 128, 0, stream>>>(Cp, b3, y3, ps, pq);
  kbn_final<<<1, 128, 0, stream>>>(ps, pq, g3, bb3, scale, shift, 128, 32);
  kbn_apply_split4<<<512, 256, 0, stream>>>((const float4*)y3, scale, shift, (ushort4*)h3h,
                                            (ushort4*)h3l, 127);

  // --- lambda head + rate (fused epilogue) ---
  kgemm3p<<<dim3(32, 1), 256, 0, stream>>>(h3h, h3l, w4th, w4tl, b4, out_rate, 128, 128, 128,
                                           nullptr, nullptr, diag);

  // --- Poisson rsample ---
  kpoisson<<<2048, 256, 0, stream>>>(u, out_rate, out_samp, sb);

  // --- reconstruction ---
  kgemm<<<dim3(32, 8), 256, 0, stream>>>(sb, dct, out_xrec, 1024, 128);
}